// Round 15
// baseline (772.275 us; speedup 1.0000x reference)
//
#include <hip/hip_runtime.h>
#include <cmath>

// ---------------------------------------------------------------------------
// Problem constants (B=8, H=W=64, C=192, 3 dilation branches of d=64, heads=64)
// ---------------------------------------------------------------------------
#define kB    8
#define kH    64
#define kW    64
#define kHW   4096          // H*W
#define kC    192
#define kD    64            // channels per dilation branch == head_dim
#define kM    (kB * kHW)    // 32768 total pixels
#define kNQKV 576           // 3*C

typedef unsigned short ushort_t;
typedef __attribute__((ext_vector_type(8))) short  s8v;   // 8 bf16 (4 VGPRs)
typedef __attribute__((ext_vector_type(4))) float  f4v;   // MFMA C/D frag

__device__ inline unsigned short bf16r(float f) {   // round-to-nearest-even
    union { float f; unsigned u; } v; v.f = f;
    unsigned u = v.u + 0x7FFFu + ((v.u >> 16) & 1u);
    return (unsigned short)(u >> 16);
}
__device__ inline float bfu(short s) {              // bf16 -> fp32
    union { unsigned u; float f; } v;
    v.u = ((unsigned)(unsigned short)s) << 16;
    return v.f;
}
// single-instruction RTNE pack: 2 f32 -> packed bf16 (gfx950 v_cvt_pk_bf16_f32;
// no builtin exists — inline asm, non-volatile so the scheduler may move it)
__device__ inline unsigned cvtpk(float lo, float hi) {
    unsigned r;
    asm("v_cvt_pk_bf16_f32 %0, %1, %2" : "=v"(r) : "v"(lo), "v"(hi));
    return r;
}

// ---------------------------------------------------------------------------
// prep_all: weight packs only (x conversion fused into qkv_mfma4). Verified.
// ---------------------------------------------------------------------------
__global__ void prep_all(const float* __restrict__ qkv_w,
                         const float* __restrict__ proj_w,
                         const float* __restrict__ def_w2,
                         const float* __restrict__ def_w3,
                         const float* __restrict__ off_w2,
                         const float* __restrict__ off_w3,
                         ushort_t* __restrict__ awb,
                         ushort_t* __restrict__ pwbp,
                         ushort_t* __restrict__ dwtb2,
                         ushort_t* __restrict__ dwtb3,
                         ushort_t* __restrict__ owtb2,
                         ushort_t* __restrict__ owtb3) {
    const int bid = blockIdx.x;
    const int tid = threadIdx.x;
    if (bid < 54) {                       // qw_pack
        int idx = bid * 256 + tid;        // 36*6*64 = 13824
        if (idx >= 36 * 6 * 64) return;
        int lane = idx & 63;
        int kc   = (idx >> 6) % 6;
        int s    = idx / 384;
        int row  = s * 16 + (lane & 15);
        int k0   = kc * 32 + (lane >> 4) * 8;
        const float* src = qkv_w + (size_t)row * kC + k0;
        ushort_t* dst = awb + (size_t)idx * 8;
#pragma unroll
        for (int j = 0; j < 8; ++j) dst[j] = bf16r(src[j]);
    } else if (bid < 72) {                // pw_pack
        int idx = (bid - 54) * 256 + tid; // 12*6*64 = 4608
        if (idx >= 12 * 6 * 64) return;
        int lane = idx & 63;
        int kc   = (idx >> 6) % 6;
        int s    = idx / 384;
        int row  = s * 16 + (lane & 15);
        int k0   = kc * 32 + (lane >> 4) * 8;
        const float* src = proj_w + (size_t)row * kC + k0;
        ushort_t* dst = pwbp + (size_t)idx * 8;
#pragma unroll
        for (int j = 0; j < 8; ++j) dst[j] = bf16r(src[j]);
    } else if (bid < 360) {               // dw_tb x2
        const float* dw = (bid < 216) ? def_w2 : def_w3;
        ushort_t* dwtb  = (bid < 216) ? dwtb2 : dwtb3;
        int l = ((bid < 216) ? (bid - 72) : (bid - 216)) * 256 + tid;  // 36864
        if (l >= kD * kD * 9) return;
        int o = l / 576;
        int c = (l / 9) % 64;
        int kk = l % 9;
        dwtb[(kk * 64 + o) * 64 + c] = bf16r(dw[l]);
    } else {                              // ow_tb x2
        const float* ow = (bid < 432) ? off_w2 : off_w3;
        ushort_t* owtb  = (bid < 432) ? owtb2 : owtb3;
        int l = ((bid < 432) ? (bid - 360) : (bid - 432)) * 256 + tid; // 18432
        if (l >= 9 * 32 * 64) return;
        int kk = l >> 11;
        int j  = (l >> 6) & 31;
        int c  = l & 63;
        owtb[l] = (j < 18) ? bf16r(ow[j * 576 + c * 9 + kk]) : (ushort_t)0;
    }
}

// ---------------------------------------------------------------------------
// Kernel 1: QKV projection GEMM, fused f32->bf16 staging + cvtpk (verified).
// UNCHANGED this round (control).
// ---------------------------------------------------------------------------
__global__ __launch_bounds__(256) void qkv_mfma4(const float* __restrict__ xf,
                                                 const ushort_t* __restrict__ awb,
                                                 ushort_t* __restrict__ qkvpx) {
    __shared__ ushort_t xs[64 * kC];            // 24576 B, swizzled rows of 384 B

    const int tid = threadIdx.x;
    const int bx  = blockIdx.x;
    const int lb  = (bx & 7) * 64 + (bx >> 3);  // XCD swizzle (G=512)
    const int m0  = lb * 64;
    const int ty3 = blockIdx.y;                 // tensor triple: channels [ty3*192, +192)

#pragma unroll
    for (int i = 0; i < 6; ++i) {
        int il = i * 256 + tid;                 // 16B chunk id, 0..1535
        int p  = il / 24;                       // pixel row in strip
        int cc = il % 24;                       // 16B chunk within row
        const float* src = xf + (size_t)(m0 + p) * kC + cc * 8;
        float4 f0 = *(const float4*)(src);
        float4 f1 = *(const float4*)(src + 4);
        uint4 v;
        v.x = cvtpk(f0.x, f0.y);
        v.y = cvtpk(f0.z, f0.w);
        v.z = cvtpk(f1.x, f1.y);
        v.w = cvtpk(f1.z, f1.w);
        int dst = p * 384 + ((cc * 16) ^ ((p & 7) << 4));
        *(uint4*)((char*)xs + dst) = v;
    }
    __syncthreads();

    const int lane = tid & 63;
    const int wave = tid >> 6;
    const int l15  = lane & 15;
    const int q    = lane >> 4;
    const int sbase = ty3 * 12 + wave * 3;      // first of 3 N-strips for this wave

    f4v acc[3][4];
#pragma unroll
    for (int i = 0; i < 3; ++i)
#pragma unroll
        for (int m = 0; m < 4; ++m) acc[i][m] = (f4v){0.f, 0.f, 0.f, 0.f};

    const ushort_t* ap = awb + ((size_t)sbase * 6 * 64 + lane) * 8;

#pragma unroll
    for (int kc = 0; kc < 6; ++kc) {
        s8v bfr[4];
#pragma unroll
        for (int m = 0; m < 4; ++m) {
            int row = m * 16 + l15;
            int col = (kc * 64 + q * 16) ^ ((l15 & 7) << 4);
            bfr[m] = *(const s8v*)((const char*)xs + row * 384 + col);
        }
#pragma unroll
        for (int i = 0; i < 3; ++i) {
            s8v a = *(const s8v*)(ap + (size_t)(i * 6 + kc) * 64 * 8);
#pragma unroll
            for (int m = 0; m < 4; ++m)
                acc[i][m] = __builtin_amdgcn_mfma_f32_16x16x32_bf16(a, bfr[m], acc[i][m], 0, 0, 0);
        }
    }

#pragma unroll
    for (int i = 0; i < 3; ++i) {
        int s   = sbase + i;
        int ty  = s >> 2;                       // tensor 0..8
        int c64 = (s & 3) * 16 + q * 4;         // channel within tensor
        ushort_t* obase = qkvpx + (size_t)ty * kM * 64 + (size_t)m0 * 64 + c64;
#pragma unroll
        for (int m = 0; m < 4; ++m) {
            f4v v = acc[i][m];
            uint2 u;
            u.x = cvtpk(v.x, v.y);
            u.y = cvtpk(v.z, v.w);
            *(uint2*)(obase + (size_t)(m * 16 + l15) * 64) = u;
        }
    }
}

// ---------------------------------------------------------------------------
// Kernel 2 (round-20, verified): offsets conv, LDS-staged k window. UNCHANGED.
// ---------------------------------------------------------------------------
__global__ __launch_bounds__(256) void off_conv_fused(const ushort_t* __restrict__ k1,
                                                      const ushort_t* __restrict__ k2,
                                                      const ushort_t* __restrict__ owtb2,
                                                      const ushort_t* __restrict__ owtb3,
                                                      const float* __restrict__ ob2,
                                                      const float* __restrict__ ob3,
                                                      float* __restrict__ offb2,
                                                      float* __restrict__ offb3) {
    __shared__ ushort_t ks[7 * 4096];           // up to 7 rows x 8192 B, swizzled

    const int bx = blockIdx.x;
    const int lb = (bx & 7) * 128 + (bx >> 3);  // XCD swizzle (G=1024)
    const int zb = lb >> 9;                     // 0: dil2, 1: dil3
    const int rest = lb & 511;
    const int b = rest >> 6;
    const int y = rest & 63;
    const int dil = 2 + zb;
    const int nr  = 2 * dil + 1;
    const int wlo = y - dil;
    const ushort_t* kpx  = zb ? k2 : k1;
    const ushort_t* owtb = zb ? owtb3 : owtb2;
    const float* obias   = zb ? ob3 : ob2;
    float* offb          = zb ? offb3 : offb2;

    const int tid  = threadIdx.x;
    const ushort_t* kb = kpx + (size_t)b * kHW * 64;

    for (int r = 0; r < nr; ++r) {
        int gy = min(max(wlo + r, 0), kH - 1);
#pragma unroll
        for (int h = 0; h < 2; ++h) {
            int chunk = h * 256 + tid;
            int xcol = chunk >> 3, cc = chunk & 7;
            int dstc = (xcol * 128 + cc * 16) ^ ((xcol & 7) << 4);
            *(uint4*)((char*)ks + r * 8192 + dstc) =
                *(const uint4*)(kb + (size_t)gy * 4096 + chunk * 8);
        }
    }
    __syncthreads();

    const int lane = tid & 63;
    const int wave = tid >> 6;
    const int l15  = lane & 15;
    const int q    = lane >> 4;
    const int px   = wave * 16 + l15;

    f4v acc[2];
    acc[0] = (f4v){0.f, 0.f, 0.f, 0.f};
    acc[1] = (f4v){0.f, 0.f, 0.f, 0.f};

#pragma unroll
    for (int kk = 0; kk < 9; ++kk) {
        const int yy = y + (kk / 3 - 1) * dil;
        const int xx = px + (kk % 3 - 1) * dil;
        const bool valid = (yy >= 0) & (yy < kH) & (xx >= 0) & (xx < kW);
        int r  = min(max(yy - wlo, 0), nr - 1);
        int xc = min(max(xx, 0), kW - 1);
        int sw = (xc & 7) << 4;
        s8v a0 = *(const s8v*)((const char*)ks + r * 8192 + ((xc * 128 + q * 16) ^ sw));
        s8v a1 = *(const s8v*)((const char*)ks + r * 8192 + ((xc * 128 + q * 16 + 64) ^ sw));
        if (!valid) {
            a0 = (s8v){0, 0, 0, 0, 0, 0, 0, 0};
            a1 = (s8v){0, 0, 0, 0, 0, 0, 0, 0};
        }
        const ushort_t* wb = owtb + (size_t)kk * 2048 + l15 * 64 + q * 8;
#pragma unroll
        for (int nbk = 0; nbk < 2; ++nbk) {
            s8v b0 = *(const s8v*)(wb + nbk * 1024);
            s8v b1 = *(const s8v*)(wb + nbk * 1024 + 32);
            acc[nbk] = __builtin_amdgcn_mfma_f32_16x16x32_bf16(a0, b0, acc[nbk], 0, 0, 0);
            acc[nbk] = __builtin_amdgcn_mfma_f32_16x16x32_bf16(a1, b1, acc[nbk], 0, 0, 0);
        }
    }
#pragma unroll
    for (int nbk = 0; nbk < 2; ++nbk) {
        int n = nbk * 16 + l15;
        if (n < 18) {
            float bias = obias[n];
            f4v v = acc[nbk];
            v.x += bias; v.y += bias; v.z += bias; v.w += bias;
            *(f4v*)&offb[((size_t)b * 18 + n) * kHW + y * kW + wave * 16 + q * 4] = v;
        }
    }
}

// ---------------------------------------------------------------------------
// Kernel 3 (round-23): deformable conv — bilinear moved to the MFMA PIPE.
// Round-22 state: ~42us, VALUBusy 53%, MfmaUtil 7% (93% idle matrix pipe).
// Linearity: sum_c W[o][c]*(sum_corner w_cr*corner_c) ==
//            sum_corner w_cr*(sum_c W[o][c]*corner_c).
// So: MFMA each RAW bf16 corner (zero unpack/convert/pack VALU) into a temp
// frag, then acc += w_corner * temp in f32. Valid per-lane because D's
// elements for a lane all belong to its own pixel column (col = l15 = px).
// Numerically drops the intermediate bf16 rounding (more accurate than ref).
// VALU/tap ~200 -> ~100; MFMA/tap 8 -> 32 (pipes co-issue, m114).
// ---------------------------------------------------------------------------
__global__ __launch_bounds__(1024) void deform_big(const ushort_t* __restrict__ k1,
                                                   const ushort_t* __restrict__ v1,
                                                   const ushort_t* __restrict__ k2,
                                                   const ushort_t* __restrict__ v2,
                                                   const float* __restrict__ offb2,
                                                   const float* __restrict__ offb3,
                                                   const ushort_t* __restrict__ dwtb2,
                                                   const ushort_t* __restrict__ dwtb3,
                                                   const float* __restrict__ db2,
                                                   const float* __restrict__ db3,
                                                   ushort_t* __restrict__ kd2,
                                                   ushort_t* __restrict__ vd2,
                                                   ushort_t* __restrict__ kd3,
                                                   ushort_t* __restrict__ vd3) {
    __shared__ ushort_t kv[12 * 4096];      // up to 12 rows x 8192 B, swizzled (96KB)
    __shared__ ushort_t wlds[5 * 4096];     // 40KB: 5 kk tiles, two-phase

    const int tid = threadIdx.x;
    const int bx  = blockIdx.x;
    const int lb  = (bx & 7) * 64 + (bx >> 3);  // XCD swizzle (G=512)
    const int zb  = lb >> 8;                // 0: dil2, 1: dil3
    const int t   = (lb >> 7) & 1;          // 0 = k, 1 = v
    const int b   = (lb >> 4) & 7;
    const int y0  = (lb & 15) * 4;          // first of 4 output rows
    const int dil = 2 + zb;
    const int nr  = 2 * dil + 6;            // staged rows (|oy|<1, 4 rows)
    const int wlo = y0 - dil - 1;

    const ushort_t* kin = zb ? k2 : k1;
    const ushort_t* vin = zb ? v2 : v1;
    const float* offbS  = zb ? offb3 : offb2;
    const ushort_t* dwtb = zb ? dwtb3 : dwtb2;
    const float* db      = zb ? db3 : db2;
    ushort_t* outp = t ? (zb ? vd3 : vd2) : (zb ? kd3 : kd2);

    const ushort_t* inb = (t ? vin : kin) + (size_t)b * kHW * 64;

    // ---- stage nr kv rows: 1024 thr = 2 rows/pass, swizzled ----
    {
        int half  = tid >> 9;               // 0/1: row within pass
        int chunk = tid & 511;              // 16B chunk within row
        int xcol  = chunk >> 3;
        int cc    = chunk & 7;
        int dstc  = (xcol * 128 + cc * 16) ^ ((xcol & 7) << 4);
        for (int r0 = 0; r0 < nr; r0 += 2) {
            int r = r0 + half;
            if (r < nr) {
                int gy = min(max(wlo + r, 0), kH - 1);
                *(uint4*)((char*)kv + r * 8192 + dstc) =
                    *(const uint4*)(inb + (size_t)gy * 4096 + chunk * 8);
            }
        }
    }
    // ---- stage weights phase A: kk 0-4 (40960 B) ----
    for (int i = tid; i < 2560; i += 1024) {
        int g = i * 16;
        uint4 v = *(const uint4*)((const char*)dwtb + g);
        int row = (g >> 7) & 63;
        *(uint4*)((char*)wlds + (g ^ ((row & 7) << 4))) = v;
    }
    __syncthreads();

    const int lane = tid & 63;
    const int wave = tid >> 6;          // 0..15
    const int ry   = wave >> 2;         // output row within quad
    const int wc   = wave & 3;          // px column
    const int l15  = lane & 15;
    const int q    = lane >> 4;
    const int y    = y0 + ry;
    const int px   = wc * 16 + l15;
    const int wsw  = (l15 & 7) << 4;
    const int wcol0 = (q * 16) ^ wsw;

    const ushort_t* inpx = inb + q * 8; // global fallback base

    f4v acc[4];
#pragma unroll
    for (int ob = 0; ob < 4; ++ob) acc[ob] = (f4v){0.f, 0.f, 0.f, 0.f};

    const float* offrow = offbS + (size_t)b * 18 * kHW + y * kW + px;
    float offv[18];
#pragma unroll
    for (int i = 0; i < 18; ++i) offv[i] = offrow[(size_t)i * kHW];

    const f4v zero4 = (f4v){0.f, 0.f, 0.f, 0.f};

    auto do_tap = [&](int kk, int kkbase) {
        float oy = offv[kk * 2 + 0];
        float ox = offv[kk * 2 + 1];
        float py  = (float)y  + (float)((kk / 3 - 1) * dil) + oy;
        float pxf = (float)px + (float)((kk % 3 - 1) * dil) + ox;
        float fy = floorf(py), fx = floorf(pxf);
        float wy = py - fy, wx = pxf - fx;
        int iy0 = (int)fy, ix0 = (int)fx;
        int iy1 = iy0 + 1, ix1 = ix0 + 1;
        int y0c = min(max(iy0, 0), kH - 1), x0c = min(max(ix0, 0), kW - 1);
        int y1c = min(max(iy1, 0), kH - 1), x1c = min(max(ix1, 0), kW - 1);
        bool vy0 = (iy0 >= 0) & (iy0 < kH), vx0 = (ix0 >= 0) & (ix0 < kW);
        bool vy1 = (iy1 >= 0) & (iy1 < kH), vx1 = (ix1 >= 0) & (ix1 < kW);
        float wgt[4];
        wgt[0] = (vy0 && vx0) ? (1.f - wy) * (1.f - wx) : 0.f;
        wgt[1] = (vy0 && vx1) ? (1.f - wy) * wx : 0.f;
        wgt[2] = (vy1 && vx0) ? wy * (1.f - wx) : 0.f;
        wgt[3] = (vy1 && vx1) ? wy * wx : 0.f;

        s8v c[8];
        if (__builtin_expect(fabsf(oy) < 1.0f, 1)) {
            int r0 = min(max(y0c - wlo, 0), nr - 1) * 8192;
            int r1 = min(max(y1c - wlo, 0), nr - 1) * 8192;
            int col0 = (x0c * 128 + q * 16) ^ ((x0c & 7) << 4);
            int col1 = (x1c * 128 + q * 16) ^ ((x1c & 7) << 4);
            int b00 = r0 + col0;
            int b01 = r0 + col1;
            int b10 = r1 + col0;
            int b11 = r1 + col1;
            c[0] = *(const s8v*)((const char*)kv + b00);
            c[1] = *(const s8v*)((const char*)kv + (b00 ^ 64));
            c[2] = *(const s8v*)((const char*)kv + b01);
            c[3] = *(const s8v*)((const char*)kv + (b01 ^ 64));
            c[4] = *(const s8v*)((const char*)kv + b10);
            c[5] = *(const s8v*)((const char*)kv + (b10 ^ 64));
            c[6] = *(const s8v*)((const char*)kv + b11);
            c[7] = *(const s8v*)((const char*)kv + (b11 ^ 64));
        } else {
            size_t i00 = (size_t)(y0c * kW + x0c) * 64;
            size_t i01 = (size_t)(y0c * kW + x1c) * 64;
            size_t i10 = (size_t)(y1c * kW + x0c) * 64;
            size_t i11 = (size_t)(y1c * kW + x1c) * 64;
            c[0] = *(const s8v*)(inpx + i00);
            c[1] = *(const s8v*)(inpx + i00 + 32);
            c[2] = *(const s8v*)(inpx + i01);
            c[3] = *(const s8v*)(inpx + i01 + 32);
            c[4] = *(const s8v*)(inpx + i10);
            c[5] = *(const s8v*)(inpx + i10 + 32);
            c[6] = *(const s8v*)(inpx + i11);
            c[7] = *(const s8v*)(inpx + i11 + 32);
        }

        // weight frags: loaded once per tap (8 ds_reads), reused by 4 corners
        const char* wkk = (const char*)wlds + (kk - kkbase) * 8192 + l15 * 128;
        s8v a0w[4], a1w[4];
#pragma unroll
        for (int obb = 0; obb < 4; ++obb) {
            a0w[obb] = *(const s8v*)(wkk + (obb * 2048 + wcol0));
            a1w[obb] = *(const s8v*)(wkk + ((obb * 2048 + wcol0) ^ 64));
        }
        // per corner: MFMA raw bf16 corner into temp, scale-add in f32
#pragma unroll
        for (int corner = 0; corner < 4; ++corner) {
            s8v clo = c[2 * corner];
            s8v chi = c[2 * corner + 1];
            float w = wgt[corner];
#pragma unroll
            for (int obb = 0; obb < 4; ++obb) {
                f4v tmp = __builtin_amdgcn_mfma_f32_16x16x32_bf16(a0w[obb], clo, zero4, 0, 0, 0);
                tmp = __builtin_amdgcn_mfma_f32_16x16x32_bf16(a1w[obb], chi, tmp, 0, 0, 0);
                acc[obb].x += w * tmp.x;
                acc[obb].y += w * tmp.y;
                acc[obb].z += w * tmp.z;
                acc[obb].w += w * tmp.w;
            }
        }
    };

    // ---- phase A: taps 0-4 ----
#pragma unroll
    for (int kk = 0; kk < 5; ++kk) do_tap(kk, 0);
    __syncthreads();
    // ---- restage weights: kk 5-8 (32768 B) ----
    for (int i = tid; i < 2048; i += 1024) {
        int g = i * 16;
        uint4 v = *(const uint4*)((const char*)dwtb + 40960 + g);
        int row = (g >> 7) & 63;
        *(uint4*)((char*)wlds + (g ^ ((row & 7) << 4))) = v;
    }
    __syncthreads();
    // ---- phase B: taps 5-8 ----
#pragma unroll
    for (int kk = 5; kk < 9; ++kk) do_tap(kk, 5);

    // store: lane holds o = obb*16 + q*4 + reg at pixel px -> bf16 pixel-major
    ushort_t* orow = outp + ((size_t)b * kHW + y * kW + px) * 64 + q * 4;
#pragma unroll
    for (int obb = 0; obb < 4; ++obb) {
        float4 bias = *(const float4*)&db[obb * 16 + q * 4];
        f4v v = acc[obb];
        uint2 u;
        u.x = cvtpk(v.x + bias.x, v.y + bias.y);
        u.y = cvtpk(v.z + bias.z, v.w + bias.w);
        *(uint2*)(orow + obb * 16) = u;
    }
}

// ---------------------------------------------------------------------------
// Kernel 4 (round-20/22, verified): attention, two-phase k->v staging.
// UNCHANGED this round (control).
// ---------------------------------------------------------------------------
__global__ __launch_bounds__(512) void attn_fused(const ushort_t* __restrict__ q0,
                                                  const ushort_t* __restrict__ k0,
                                                  const ushort_t* __restrict__ v0,
                                                  const ushort_t* __restrict__ q1,
                                                  const ushort_t* __restrict__ kd2,
                                                  const ushort_t* __restrict__ vd2,
                                                  const ushort_t* __restrict__ q2,
                                                  const ushort_t* __restrict__ kd3,
                                                  const ushort_t* __restrict__ vd3,
                                                  ushort_t* __restrict__ aopx) {
    __shared__ ushort_t kvs[8 * 4096];      // 64KB: k then v (two-phase)

    const int tid = threadIdx.x;
    const int bx  = blockIdx.x;
    const int lb  = (bx & 7) * 96 + (bx >> 3);  // XCD swizzle (G=768)
    const int zb  = lb >> 8;                // branch 0,1,2
    const int rest = lb & 255;
    const int b   = rest >> 5;
    const int y0  = (rest & 31) * 2;        // first of 2 output rows
    const int dil = zb + 1;
    const int nr  = 2 * dil + 2;            // staged rows
    const int wlo = y0 - dil;

    const ushort_t* qpx = (zb == 0) ? q0 : (zb == 1) ? q1 : q2;
    const ushort_t* kpx = (zb == 0) ? k0 : (zb == 1) ? kd2 : kd3;
    const ushort_t* vpx = (zb == 0) ? v0 : (zb == 1) ? vd2 : vd3;

    const size_t pbase = (size_t)b * kHW;
    const ushort_t* kb = kpx + pbase * 64;
    const ushort_t* vb = vpx + pbase * 64;

    const int stx  = tid >> 3;
    const int stcc = tid & 7;
    const int dstc = (stx * 128 + stcc * 16) ^ ((stx & 7) << 4);

    // ---- phase 1: stage k rows ----
    for (int r = 0; r < nr; ++r) {
        int gy = min(max(wlo + r, 0), kH - 1);
        *(uint4*)((char*)kvs + r * 8192 + dstc) = *(const uint4*)(kb + (size_t)gy * 4096 + tid * 8);
    }
    __syncthreads();

    const int wave = tid >> 6;          // 0..7
    const int l    = tid & 63;
    const int ry   = wave >> 2;         // row within pair
    const int wc   = wave & 3;          // 16-px column group
    const int pxq  = l >> 2;            // 16 pixels per wave
    const int cg   = l & 3;             // 4 channel-groups of 16 ch
    const int y  = y0 + ry;
    const int x_ = wc * 16 + pxq;
    const int p  = y * kW + x_;

    const ushort_t* qb = qpx + (pbase + p) * 64 + cg * 16;
    s8v qv0 = *(const s8v*)qb;
    s8v qv1 = *(const s8v*)(qb + 8);
    float qf[16];
#pragma unroll
    for (int j = 0; j < 8; ++j) { qf[j] = bfu(qv0[j]); qf[8 + j] = bfu(qv1[j]); }

    int a0s[9], a1s[9];
    float msk[9];
#pragma unroll
    for (int kk = 0; kk < 9; ++kk) {
        int dy = (kk / 3 - 1) * dil, dx = (kk % 3 - 1) * dil;
        int yy = y + dy, xx = x_ + dx;
        bool v = (yy >= 0) & (yy < kH) & (xx >= 0) & (xx < kW);
        msk[kk] = v ? 1.f : 0.f;
        int r  = min(max(yy - wlo, 0), nr - 1);
        int xc = min(max(xx, 0), kW - 1);
        int sw = (xc & 7) << 4;
        a0s[kk] = r * 8192 + ((xc * 128 + cg * 32) ^ sw);
        a1s[kk] = r * 8192 + ((xc * 128 + cg * 32 + 16) ^ sw);
    }

    float e[9];
#pragma unroll
    for (int kk = 0; kk < 9; ++kk) {
        s8v k0v = *(const s8v*)((const char*)kvs + a0s[kk]);
        s8v k1v = *(const s8v*)((const char*)kvs + a1s[kk]);
        float s = 0.f;
#pragma unroll
        for (int j = 0; j < 8; ++j) {
            s += qf[j] * bfu(k0v[j]);
            s += qf[8 + j] * bfu(k1v[j]);
        }
        s += __shfl_xor(s, 1);
        s += __shfl_xor(s, 2);
        e[kk] = s * 0.125f * msk[kk];
    }
    float mx = -1e30f;
#pragma unroll
    for (int kk = 0; kk < 9; ++kk) mx = fmaxf(mx, e[kk]);
    float ssum = 0.f;
#pragma unroll
    for (int kk = 0; kk < 9; ++kk) { e[kk] = __expf(e[kk] - mx); ssum += e[kk]; }
    float inv = 1.f / ssum;
#pragma unroll
    for (int kk = 0; kk < 9; ++kk) e[kk] = e[kk] * inv * msk[kk];

    __syncthreads();                     // all k reads done
    // ---- phase 2: restage with v rows ----
    for (int r = 0; r < nr; ++r) {
        int gy = min(max(wlo + r, 0), kH - 1);
        *(uint4*)((char*)kvs + r * 8192 + dstc) = *(const uint4*)(vb + (size_t)gy * 4096 + tid * 8);
    }
    __syncthreads();

    float acc[16];
#pragma unroll
    for (int j = 0; j < 16; ++j) acc[j] = 0.f;
#pragma unroll
    for (int kk = 0; kk < 9; ++kk) {
        s8v v0v = *(const s8v*)((const char*)kvs + a0s[kk]);
        s8v v1v = *(const s8v*)((const char*)kvs + a1s[kk]);
        float w = e[kk];
#pragma unroll
        for (int j = 0; j < 8; ++j) {
            acc[j] += w * bfu(v0v[j]);
            acc[8 + j] += w * bfu(v1v[j]);
        }
    }
    unsigned u[8];
#pragma unroll
    for (int i = 0; i < 8; ++i)
        u[i] = cvtpk(acc[2 * i], acc[2 * i + 1]);
    ushort_t* ob = aopx + (pbase + p) * kC + zb * 64 + cg * 16;
    *(uint4*)ob = make_uint4(u[0], u[1], u[2], u[3]);
    *(uint4*)(ob + 8) = make_uint4(u[4], u[5], u[6], u[7]);
}

// ---------------------------------------------------------------------------
// Kernel 5 (verified): output projection, LDS-staged GEMM. UNCHANGED.
// ---------------------------------------------------------------------------
__global__ __launch_bounds__(256) void proj_mfma3(const ushort_t* __restrict__ aopx,
                                                  const ushort_t* __restrict__ pwbp,
                                                  const float* __restrict__ pb,
                                                  float* __restrict__ out) {
    __shared__ ushort_t xs[64 * kC];            // 24576 B, swizzled rows of 384 B

    const int tid = threadIdx.x;
    const int bx  = blockIdx.x;
    const int lb  = (bx & 7) * 64 + (bx >> 3);  // XCD swizzle (G=512)
    const int m0  = lb * 64;

#pragma unroll
    for (int i = 0; i < 6; ++i) {
        int il = i * 256 + tid;                 // 16B chunk id, 0..1535
        int p  = il / 24;                       // pixel row in strip
        int cc = il % 24;                       // 16B chunk within row
        uint4 v = *(const uint4*)(aopx + (size_t)(m0 + p) * kC + cc * 8);
        int dst = p * 384 + ((cc * 16) ^ ((p & 7) << 4));
        *(uint4*)((char*)xs + dst) = v;
    }
    __syncthreads();

    const int lane = tid & 63;
    const int wave = tid >> 6;
    const int l15  = lane & 15;
    const int q    = lane >> 4;
    const int sbase = wave * 3;                 // strips 0..11, 3 per wave

    f4v acc[3][4];
#pragma unroll
    for (int i = 0; i < 3; ++i)
#pragma unroll
        for (int m = 0; m < 4; ++m) acc[i][m] = (f4v){0.f, 0.f, 0.f, 0.f};

    const ushort_t* ap = pwbp + ((size_t)sbase * 6 * 64 + lane) * 8;

#pragma unroll
    for (int kc = 0; kc < 6; ++kc) {
        s8v bfr[4];
#pragma unroll
        for (int m = 0; m < 4; ++m) {
            int row = m * 16 + l15;
            int col = (kc * 64 + q * 16) ^ ((l15 & 7) << 4);
            bfr[m] = *(const s8v*)((const char*)xs + row * 384 + col);
        }
#pragma unroll
        for (int i = 0; i < 3; ++i) {
            s8v a = *(const s8v*)(ap + (size_t)(i * 6 + kc) * 64 * 8);
#pragma unroll
            for (int m = 0; m < 4; ++m)
                acc[i][m] = __builtin_amdgcn_mfma_f32_16x16x32_bf16(a, bfr[m], acc[i][m], 0, 0, 0);
        }
    }

#pragma unroll
    for (int i = 0; i < 3; ++i) {
        int s  = sbase + i;
        int n0 = s * 16 + q * 4;
        float4 bias = *(const float4*)&pb[n0];
#pragma unroll
        for (int m = 0; m < 4; ++m) {
            f4v v = acc[i][m];
            v.x += bias.x; v.y += bias.y; v.z += bias.z; v.w += bias.w;
            *(f4v*)&out[(size_t)(m0 + m * 16 + l15) * kC + n0] = v;
        }
    }
}

// ---------------------------------------------------------------------------
// Host launcher.  Workspace ~72 MB.
// 6 dispatches: prep_all, qkv(fused cvt), off_fused, deform_big, attn_fused, proj.
// ---------------------------------------------------------------------------
extern "C" void kernel_launch(void* const* d_in, const int* in_sizes, int n_in,
                              void* d_out, int out_size, void* d_ws, size_t ws_size,
                              hipStream_t stream) {
    const float* x      = (const float*)d_in[0];
    const float* qkv_w  = (const float*)d_in[1];
    const float* proj_w = (const float*)d_in[2];
    const float* proj_b = (const float*)d_in[3];
    const float* off_w2 = (const float*)d_in[4];
    const float* off_b2 = (const float*)d_in[5];
    const float* def_w2 = (const float*)d_in[6];
    const float* def_b2 = (const float*)d_in[7];
    const float* off_w3 = (const float*)d_in[8];
    const float* off_b3 = (const float*)d_in[9];
    const float* def_w3 = (const float*)d_in[10];
    const float* def_b3 = (const float*)d_in[11];
    float* out = (float*)d_out;

    float* ws    = (float*)d_ws;
    float* offb2 = ws;                              // 18 * M
    float* offb3 = offb2 + (size_t)18 * kM;         // 18 * M
    ushort_t* us = (ushort_t*)(offb3 + (size_t)18 * kM);
    ushort_t* qkvpx  = us;  us += (size_t)9 * kM * 64;
    ushort_t* kd2    = us;  us += (size_t)kM * 64;
    ushort_t* vd2    = us;  us += (size_t)kM * 64;
    ushort_t* kd3    = us;  us += (size_t)kM * 64;
    ushort_t* vd3    = us;  us += (size_t)kM * 64;
    ushort_t* aopx   = us;  us += (size_t)kM * kC;
    ushort_t* awb    = us;  us += (size_t)kNQKV * kC;   // 36*6*64*8 == 576*192
    ushort_t* pwbp   = us;  us += (size_t)kC * kC;      // 12*6*64*8 == 192*192
    ushort_t* dwtb2  = us;  us += kD * kD * 9;
    ushort_t* dwtb3  = us;  us += kD * kD * 9;
    ushort_t* owtb2  = us;  us += 9 * 32 * 64;
    ushort_t* owtb3  = us;  us += 9 * 32 * 64;

    // 0. weight packs only (x conversion fused into qkv)
    prep_all<<<504, 256, 0, stream>>>(qkv_w, proj_w, def_w2, def_w3, off_w2, off_w3,
                                      awb, pwbp, dwtb2, dwtb3, owtb2, owtb3);

    // per-tensor pixel-major slices
    ushort_t* q0 = qkvpx;
    ushort_t* q1 = qkvpx + (size_t)1 * kM * 64;
    ushort_t* q2 = qkvpx + (size_t)2 * kM * 64;
    ushort_t* k0 = qkvpx + (size_t)3 * kM * 64;
    ushort_t* k1 = qkvpx + (size_t)4 * kM * 64;
    ushort_t* k2 = qkvpx + (size_t)5 * kM * 64;
    ushort_t* v0 = qkvpx + (size_t)6 * kM * 64;
    ushort_t* v1 = qkvpx + (size_t)7 * kM * 64;
    ushort_t* v2 = qkvpx + (size_t)8 * kM * 64;

    // 1. QKV projection with fused f32->bf16 staging
    qkv_mfma4<<<dim3(kM / 64, 3), 256, 0, stream>>>(x, awb, qkvpx);

    // 2. offsets conv, both branches, LDS-staged (one dispatch)
    off_conv_fused<<<1024, 256, 0, stream>>>(k1, k2, owtb2, owtb3,
                                             off_b2, off_b3, offb2, offb3);

    // 3. deformable conv, both branches, 16-wave blocks, corner-MFMA bilinear
    deform_big<<<512, 1024, 0, stream>>>(k1, v1, k2, v2, offb2, offb3,
                                         dwtb2, dwtb3, def_b2, def_b3,
                                         kd2, vd2, kd3, vd3);

    // 4. attention, all three branches, two-phase k/v staging (one dispatch)
    attn_fused<<<768, 512, 0, stream>>>(q0, k0, v0, q1, kd2, vd2, q2, kd3, vd3, aopx);

    // 5. output projection (LDS-staged bf16 MFMA, fp32 out)
    proj_mfma3<<<512, 256, 0, stream>>>(aopx, pwbp, proj_b, out);
}

// Round 16
// 195.272 us; speedup vs baseline: 3.9549x; 3.9549x over previous
//
#include <hip/hip_runtime.h>
#include <cmath>

// ---------------------------------------------------------------------------
// Problem constants (B=8, H=W=64, C=192, 3 dilation branches of d=64, heads=64)
// ---------------------------------------------------------------------------
#define kB    8
#define kH    64
#define kW    64
#define kHW   4096          // H*W
#define kC    192
#define kD    64            // channels per dilation branch == head_dim
#define kM    (kB * kHW)    // 32768 total pixels
#define kNQKV 576           // 3*C

typedef unsigned short ushort_t;
typedef __attribute__((ext_vector_type(8))) short  s8v;   // 8 bf16 (4 VGPRs)
typedef __attribute__((ext_vector_type(4))) float  f4v;   // MFMA C/D frag
typedef __attribute__((ext_vector_type(2))) float  f2v;   // packed f32 pair

__device__ inline unsigned short bf16r(float f) {   // round-to-nearest-even
    union { float f; unsigned u; } v; v.f = f;
    unsigned u = v.u + 0x7FFFu + ((v.u >> 16) & 1u);
    return (unsigned short)(u >> 16);
}
__device__ inline float bfu(short s) {              // bf16 -> fp32
    union { unsigned u; float f; } v;
    v.u = ((unsigned)(unsigned short)s) << 16;
    return v.f;
}
__device__ inline f2v bfu2(unsigned u) {            // 2 packed bf16 -> f2v
    union { unsigned u; float f; } lo, hi;
    lo.u = u << 16;
    hi.u = u & 0xFFFF0000u;
    return (f2v){lo.f, hi.f};
}
// single-instruction RTNE pack: 2 f32 -> packed bf16 (gfx950 v_cvt_pk_bf16_f32)
__device__ inline unsigned cvtpk(float lo, float hi) {
    unsigned r;
    asm("v_cvt_pk_bf16_f32 %0, %1, %2" : "=v"(r) : "v"(lo), "v"(hi));
    return r;
}

// ---------------------------------------------------------------------------
// prep_all: weight packs only (x conversion fused into qkv_mfma4). Verified.
// ---------------------------------------------------------------------------
__global__ void prep_all(const float* __restrict__ qkv_w,
                         const float* __restrict__ proj_w,
                         const float* __restrict__ def_w2,
                         const float* __restrict__ def_w3,
                         const float* __restrict__ off_w2,
                         const float* __restrict__ off_w3,
                         ushort_t* __restrict__ awb,
                         ushort_t* __restrict__ pwbp,
                         ushort_t* __restrict__ dwtb2,
                         ushort_t* __restrict__ dwtb3,
                         ushort_t* __restrict__ owtb2,
                         ushort_t* __restrict__ owtb3) {
    const int bid = blockIdx.x;
    const int tid = threadIdx.x;
    if (bid < 54) {                       // qw_pack
        int idx = bid * 256 + tid;        // 36*6*64 = 13824
        if (idx >= 36 * 6 * 64) return;
        int lane = idx & 63;
        int kc   = (idx >> 6) % 6;
        int s    = idx / 384;
        int row  = s * 16 + (lane & 15);
        int k0   = kc * 32 + (lane >> 4) * 8;
        const float* src = qkv_w + (size_t)row * kC + k0;
        ushort_t* dst = awb + (size_t)idx * 8;
#pragma unroll
        for (int j = 0; j < 8; ++j) dst[j] = bf16r(src[j]);
    } else if (bid < 72) {                // pw_pack
        int idx = (bid - 54) * 256 + tid; // 12*6*64 = 4608
        if (idx >= 12 * 6 * 64) return;
        int lane = idx & 63;
        int kc   = (idx >> 6) % 6;
        int s    = idx / 384;
        int row  = s * 16 + (lane & 15);
        int k0   = kc * 32 + (lane >> 4) * 8;
        const float* src = proj_w + (size_t)row * kC + k0;
        ushort_t* dst = pwbp + (size_t)idx * 8;
#pragma unroll
        for (int j = 0; j < 8; ++j) dst[j] = bf16r(src[j]);
    } else if (bid < 360) {               // dw_tb x2
        const float* dw = (bid < 216) ? def_w2 : def_w3;
        ushort_t* dwtb  = (bid < 216) ? dwtb2 : dwtb3;
        int l = ((bid < 216) ? (bid - 72) : (bid - 216)) * 256 + tid;  // 36864
        if (l >= kD * kD * 9) return;
        int o = l / 576;
        int c = (l / 9) % 64;
        int kk = l % 9;
        dwtb[(kk * 64 + o) * 64 + c] = bf16r(dw[l]);
    } else {                              // ow_tb x2
        const float* ow = (bid < 432) ? off_w2 : off_w3;
        ushort_t* owtb  = (bid < 432) ? owtb2 : owtb3;
        int l = ((bid < 432) ? (bid - 360) : (bid - 432)) * 256 + tid; // 18432
        if (l >= 9 * 32 * 64) return;
        int kk = l >> 11;
        int j  = (l >> 6) & 31;
        int c  = l & 63;
        owtb[l] = (j < 18) ? bf16r(ow[j * 576 + c * 9 + kk]) : (ushort_t)0;
    }
}

// ---------------------------------------------------------------------------
// Kernel 1: QKV projection GEMM, fused f32->bf16 staging + cvtpk (verified).
// ---------------------------------------------------------------------------
__global__ __launch_bounds__(256) void qkv_mfma4(const float* __restrict__ xf,
                                                 const ushort_t* __restrict__ awb,
                                                 ushort_t* __restrict__ qkvpx) {
    __shared__ ushort_t xs[64 * kC];            // 24576 B, swizzled rows of 384 B

    const int tid = threadIdx.x;
    const int bx  = blockIdx.x;
    const int lb  = (bx & 7) * 64 + (bx >> 3);  // XCD swizzle (G=512)
    const int m0  = lb * 64;
    const int ty3 = blockIdx.y;                 // tensor triple: channels [ty3*192, +192)

#pragma unroll
    for (int i = 0; i < 6; ++i) {
        int il = i * 256 + tid;                 // 16B chunk id, 0..1535
        int p  = il / 24;                       // pixel row in strip
        int cc = il % 24;                       // 16B chunk within row
        const float* src = xf + (size_t)(m0 + p) * kC + cc * 8;
        float4 f0 = *(const float4*)(src);
        float4 f1 = *(const float4*)(src + 4);
        uint4 v;
        v.x = cvtpk(f0.x, f0.y);
        v.y = cvtpk(f0.z, f0.w);
        v.z = cvtpk(f1.x, f1.y);
        v.w = cvtpk(f1.z, f1.w);
        int dst = p * 384 + ((cc * 16) ^ ((p & 7) << 4));
        *(uint4*)((char*)xs + dst) = v;
    }
    __syncthreads();

    const int lane = tid & 63;
    const int wave = tid >> 6;
    const int l15  = lane & 15;
    const int q    = lane >> 4;
    const int sbase = ty3 * 12 + wave * 3;      // first of 3 N-strips for this wave

    f4v acc[3][4];
#pragma unroll
    for (int i = 0; i < 3; ++i)
#pragma unroll
        for (int m = 0; m < 4; ++m) acc[i][m] = (f4v){0.f, 0.f, 0.f, 0.f};

    const ushort_t* ap = awb + ((size_t)sbase * 6 * 64 + lane) * 8;

#pragma unroll
    for (int kc = 0; kc < 6; ++kc) {
        s8v bfr[4];
#pragma unroll
        for (int m = 0; m < 4; ++m) {
            int row = m * 16 + l15;
            int col = (kc * 64 + q * 16) ^ ((l15 & 7) << 4);
            bfr[m] = *(const s8v*)((const char*)xs + row * 384 + col);
        }
#pragma unroll
        for (int i = 0; i < 3; ++i) {
            s8v a = *(const s8v*)(ap + (size_t)(i * 6 + kc) * 64 * 8);
#pragma unroll
            for (int m = 0; m < 4; ++m)
                acc[i][m] = __builtin_amdgcn_mfma_f32_16x16x32_bf16(a, bfr[m], acc[i][m], 0, 0, 0);
        }
    }

#pragma unroll
    for (int i = 0; i < 3; ++i) {
        int s   = sbase + i;
        int ty  = s >> 2;                       // tensor 0..8
        int c64 = (s & 3) * 16 + q * 4;         // channel within tensor
        ushort_t* obase = qkvpx + (size_t)ty * kM * 64 + (size_t)m0 * 64 + c64;
#pragma unroll
        for (int m = 0; m < 4; ++m) {
            f4v v = acc[i][m];
            uint2 u;
            u.x = cvtpk(v.x, v.y);
            u.y = cvtpk(v.z, v.w);
            *(uint2*)(obase + (size_t)(m * 16 + l15) * 64) = u;
        }
    }
}

// ---------------------------------------------------------------------------
// Kernel 2 (round-20, verified): offsets conv, LDS-staged k window. UNCHANGED.
// ---------------------------------------------------------------------------
__global__ __launch_bounds__(256) void off_conv_fused(const ushort_t* __restrict__ k1,
                                                      const ushort_t* __restrict__ k2,
                                                      const ushort_t* __restrict__ owtb2,
                                                      const ushort_t* __restrict__ owtb3,
                                                      const float* __restrict__ ob2,
                                                      const float* __restrict__ ob3,
                                                      float* __restrict__ offb2,
                                                      float* __restrict__ offb3) {
    __shared__ ushort_t ks[7 * 4096];           // up to 7 rows x 8192 B, swizzled

    const int bx = blockIdx.x;
    const int lb = (bx & 7) * 128 + (bx >> 3);  // XCD swizzle (G=1024)
    const int zb = lb >> 9;                     // 0: dil2, 1: dil3
    const int rest = lb & 511;
    const int b = rest >> 6;
    const int y = rest & 63;
    const int dil = 2 + zb;
    const int nr  = 2 * dil + 1;
    const int wlo = y - dil;
    const ushort_t* kpx  = zb ? k2 : k1;
    const ushort_t* owtb = zb ? owtb3 : owtb2;
    const float* obias   = zb ? ob3 : ob2;
    float* offb          = zb ? offb3 : offb2;

    const int tid  = threadIdx.x;
    const ushort_t* kb = kpx + (size_t)b * kHW * 64;

    for (int r = 0; r < nr; ++r) {
        int gy = min(max(wlo + r, 0), kH - 1);
#pragma unroll
        for (int h = 0; h < 2; ++h) {
            int chunk = h * 256 + tid;
            int xcol = chunk >> 3, cc = chunk & 7;
            int dstc = (xcol * 128 + cc * 16) ^ ((xcol & 7) << 4);
            *(uint4*)((char*)ks + r * 8192 + dstc) =
                *(const uint4*)(kb + (size_t)gy * 4096 + chunk * 8);
        }
    }
    __syncthreads();

    const int lane = tid & 63;
    const int wave = tid >> 6;
    const int l15  = lane & 15;
    const int q    = lane >> 4;
    const int px   = wave * 16 + l15;

    f4v acc[2];
    acc[0] = (f4v){0.f, 0.f, 0.f, 0.f};
    acc[1] = (f4v){0.f, 0.f, 0.f, 0.f};

#pragma unroll
    for (int kk = 0; kk < 9; ++kk) {
        const int yy = y + (kk / 3 - 1) * dil;
        const int xx = px + (kk % 3 - 1) * dil;
        const bool valid = (yy >= 0) & (yy < kH) & (xx >= 0) & (xx < kW);
        int r  = min(max(yy - wlo, 0), nr - 1);
        int xc = min(max(xx, 0), kW - 1);
        int sw = (xc & 7) << 4;
        s8v a0 = *(const s8v*)((const char*)ks + r * 8192 + ((xc * 128 + q * 16) ^ sw));
        s8v a1 = *(const s8v*)((const char*)ks + r * 8192 + ((xc * 128 + q * 16 + 64) ^ sw));
        if (!valid) {
            a0 = (s8v){0, 0, 0, 0, 0, 0, 0, 0};
            a1 = (s8v){0, 0, 0, 0, 0, 0, 0, 0};
        }
        const ushort_t* wb = owtb + (size_t)kk * 2048 + l15 * 64 + q * 8;
#pragma unroll
        for (int nbk = 0; nbk < 2; ++nbk) {
            s8v b0 = *(const s8v*)(wb + nbk * 1024);
            s8v b1 = *(const s8v*)(wb + nbk * 1024 + 32);
            acc[nbk] = __builtin_amdgcn_mfma_f32_16x16x32_bf16(a0, b0, acc[nbk], 0, 0, 0);
            acc[nbk] = __builtin_amdgcn_mfma_f32_16x16x32_bf16(a1, b1, acc[nbk], 0, 0, 0);
        }
    }
#pragma unroll
    for (int nbk = 0; nbk < 2; ++nbk) {
        int n = nbk * 16 + l15;
        if (n < 18) {
            float bias = obias[n];
            f4v v = acc[nbk];
            v.x += bias; v.y += bias; v.z += bias; v.w += bias;
            *(f4v*)&offb[((size_t)b * 18 + n) * kHW + y * kW + wave * 16 + q * 4] = v;
        }
    }
}

// ---------------------------------------------------------------------------
// Kernel 3 (REVERTED to round-22 verified form, ~42us): deformable conv,
// 16-wave blocks, VALU bilinear with cvtpk pack.
// Round-23's corner-MFMA variant spilled to scratch (FETCH 13MB->825MB,
// 613us) — hoisted weight frags blew the VGPR budget at 1024-thr blocks.
// Theory class closed: bilinear stays on the VALU pipe.
// ---------------------------------------------------------------------------
__global__ __launch_bounds__(1024) void deform_big(const ushort_t* __restrict__ k1,
                                                   const ushort_t* __restrict__ v1,
                                                   const ushort_t* __restrict__ k2,
                                                   const ushort_t* __restrict__ v2,
                                                   const float* __restrict__ offb2,
                                                   const float* __restrict__ offb3,
                                                   const ushort_t* __restrict__ dwtb2,
                                                   const ushort_t* __restrict__ dwtb3,
                                                   const float* __restrict__ db2,
                                                   const float* __restrict__ db3,
                                                   ushort_t* __restrict__ kd2,
                                                   ushort_t* __restrict__ vd2,
                                                   ushort_t* __restrict__ kd3,
                                                   ushort_t* __restrict__ vd3) {
    __shared__ ushort_t kv[12 * 4096];      // up to 12 rows x 8192 B, swizzled (96KB)
    __shared__ ushort_t wlds[5 * 4096];     // 40KB: 5 kk tiles, two-phase

    const int tid = threadIdx.x;
    const int bx  = blockIdx.x;
    const int lb  = (bx & 7) * 64 + (bx >> 3);  // XCD swizzle (G=512)
    const int zb  = lb >> 8;                // 0: dil2, 1: dil3
    const int t   = (lb >> 7) & 1;          // 0 = k, 1 = v
    const int b   = (lb >> 4) & 7;
    const int y0  = (lb & 15) * 4;          // first of 4 output rows
    const int dil = 2 + zb;
    const int nr  = 2 * dil + 6;            // staged rows (|oy|<1, 4 rows)
    const int wlo = y0 - dil - 1;

    const ushort_t* kin = zb ? k2 : k1;
    const ushort_t* vin = zb ? v2 : v1;
    const float* offbS  = zb ? offb3 : offb2;
    const ushort_t* dwtb = zb ? dwtb3 : dwtb2;
    const float* db      = zb ? db3 : db2;
    ushort_t* outp = t ? (zb ? vd3 : vd2) : (zb ? kd3 : kd2);

    const ushort_t* inb = (t ? vin : kin) + (size_t)b * kHW * 64;

    // ---- stage nr kv rows: 1024 thr = 2 rows/pass, swizzled ----
    {
        int half  = tid >> 9;               // 0/1: row within pass
        int chunk = tid & 511;              // 16B chunk within row
        int xcol  = chunk >> 3;
        int cc    = chunk & 7;
        int dstc  = (xcol * 128 + cc * 16) ^ ((xcol & 7) << 4);
        for (int r0 = 0; r0 < nr; r0 += 2) {
            int r = r0 + half;
            if (r < nr) {
                int gy = min(max(wlo + r, 0), kH - 1);
                *(uint4*)((char*)kv + r * 8192 + dstc) =
                    *(const uint4*)(inb + (size_t)gy * 4096 + chunk * 8);
            }
        }
    }
    // ---- stage weights phase A: kk 0-4 (40960 B) ----
    for (int i = tid; i < 2560; i += 1024) {
        int g = i * 16;
        uint4 v = *(const uint4*)((const char*)dwtb + g);
        int row = (g >> 7) & 63;
        *(uint4*)((char*)wlds + (g ^ ((row & 7) << 4))) = v;
    }
    __syncthreads();

    const int lane = tid & 63;
    const int wave = tid >> 6;          // 0..15
    const int ry   = wave >> 2;         // output row within quad
    const int wc   = wave & 3;          // px column
    const int l15  = lane & 15;
    const int q    = lane >> 4;
    const int y    = y0 + ry;
    const int px   = wc * 16 + l15;
    const int wsw  = (l15 & 7) << 4;
    const int wcol0 = (q * 16) ^ wsw;

    const ushort_t* inpx = inb + q * 8; // global fallback base

    f4v acc[4];
#pragma unroll
    for (int ob = 0; ob < 4; ++ob) acc[ob] = (f4v){0.f, 0.f, 0.f, 0.f};

    const float* offrow = offbS + (size_t)b * 18 * kHW + y * kW + px;
    float offv[18];
#pragma unroll
    for (int i = 0; i < 18; ++i) offv[i] = offrow[(size_t)i * kHW];

    auto do_tap = [&](int kk, int kkbase) {
        float oy = offv[kk * 2 + 0];
        float ox = offv[kk * 2 + 1];
        float py  = (float)y  + (float)((kk / 3 - 1) * dil) + oy;
        float pxf = (float)px + (float)((kk % 3 - 1) * dil) + ox;
        float fy = floorf(py), fx = floorf(pxf);
        float wy = py - fy, wx = pxf - fx;
        int iy0 = (int)fy, ix0 = (int)fx;
        int iy1 = iy0 + 1, ix1 = ix0 + 1;
        int y0c = min(max(iy0, 0), kH - 1), x0c = min(max(ix0, 0), kW - 1);
        int y1c = min(max(iy1, 0), kH - 1), x1c = min(max(ix1, 0), kW - 1);
        bool vy0 = (iy0 >= 0) & (iy0 < kH), vx0 = (ix0 >= 0) & (ix0 < kW);
        bool vy1 = (iy1 >= 0) & (iy1 < kH), vx1 = (ix1 >= 0) & (ix1 < kW);
        float w0 = (vy0 && vx0) ? (1.f - wy) * (1.f - wx) : 0.f;
        float w1 = (vy0 && vx1) ? (1.f - wy) * wx : 0.f;
        float w2 = (vy1 && vx0) ? wy * (1.f - wx) : 0.f;
        float w3 = (vy1 && vx1) ? wy * wx : 0.f;

        s8v c[8];
        if (__builtin_expect(fabsf(oy) < 1.0f, 1)) {
            int r0 = min(max(y0c - wlo, 0), nr - 1) * 8192;
            int r1 = min(max(y1c - wlo, 0), nr - 1) * 8192;
            int col0 = (x0c * 128 + q * 16) ^ ((x0c & 7) << 4);
            int col1 = (x1c * 128 + q * 16) ^ ((x1c & 7) << 4);
            int b00 = r0 + col0;
            int b01 = r0 + col1;
            int b10 = r1 + col0;
            int b11 = r1 + col1;
            c[0] = *(const s8v*)((const char*)kv + b00);
            c[1] = *(const s8v*)((const char*)kv + (b00 ^ 64));
            c[2] = *(const s8v*)((const char*)kv + b01);
            c[3] = *(const s8v*)((const char*)kv + (b01 ^ 64));
            c[4] = *(const s8v*)((const char*)kv + b10);
            c[5] = *(const s8v*)((const char*)kv + (b10 ^ 64));
            c[6] = *(const s8v*)((const char*)kv + b11);
            c[7] = *(const s8v*)((const char*)kv + (b11 ^ 64));
        } else {
            size_t i00 = (size_t)(y0c * kW + x0c) * 64;
            size_t i01 = (size_t)(y0c * kW + x1c) * 64;
            size_t i10 = (size_t)(y1c * kW + x0c) * 64;
            size_t i11 = (size_t)(y1c * kW + x1c) * 64;
            c[0] = *(const s8v*)(inpx + i00);
            c[1] = *(const s8v*)(inpx + i00 + 32);
            c[2] = *(const s8v*)(inpx + i01);
            c[3] = *(const s8v*)(inpx + i01 + 32);
            c[4] = *(const s8v*)(inpx + i10);
            c[5] = *(const s8v*)(inpx + i10 + 32);
            c[6] = *(const s8v*)(inpx + i11);
            c[7] = *(const s8v*)(inpx + i11 + 32);
        }

        // bilinear in packed f32; pack via v_cvt_pk_bf16_f32
        const f2v w0v = {w0, w0}, w1v = {w1, w1}, w2v = {w2, w2}, w3v = {w3, w3};
        s8v b0, b1;
#pragma unroll
        for (int jp = 0; jp < 4; ++jp) {
            f2v a0 = w0v * bfu2(((const unsigned*)&c[0])[jp])
                   + w1v * bfu2(((const unsigned*)&c[2])[jp])
                   + w2v * bfu2(((const unsigned*)&c[4])[jp])
                   + w3v * bfu2(((const unsigned*)&c[6])[jp]);
            f2v a1 = w0v * bfu2(((const unsigned*)&c[1])[jp])
                   + w1v * bfu2(((const unsigned*)&c[3])[jp])
                   + w2v * bfu2(((const unsigned*)&c[5])[jp])
                   + w3v * bfu2(((const unsigned*)&c[7])[jp]);
            ((unsigned*)&b0)[jp] = cvtpk(a0.x, a0.y);
            ((unsigned*)&b1)[jp] = cvtpk(a1.x, a1.y);
        }
        const char* wkk = (const char*)wlds + (kk - kkbase) * 8192 + l15 * 128;
#pragma unroll
        for (int obb = 0; obb < 4; ++obb) {
            s8v a0w = *(const s8v*)(wkk + (obb * 2048 + wcol0));
            s8v a1w = *(const s8v*)(wkk + ((obb * 2048 + wcol0) ^ 64));
            acc[obb] = __builtin_amdgcn_mfma_f32_16x16x32_bf16(a0w, b0, acc[obb], 0, 0, 0);
            acc[obb] = __builtin_amdgcn_mfma_f32_16x16x32_bf16(a1w, b1, acc[obb], 0, 0, 0);
        }
    };

    // ---- phase A: taps 0-4 ----
#pragma unroll
    for (int kk = 0; kk < 5; ++kk) do_tap(kk, 0);
    __syncthreads();
    // ---- restage weights: kk 5-8 (32768 B) ----
    for (int i = tid; i < 2048; i += 1024) {
        int g = i * 16;
        uint4 v = *(const uint4*)((const char*)dwtb + 40960 + g);
        int row = (g >> 7) & 63;
        *(uint4*)((char*)wlds + (g ^ ((row & 7) << 4))) = v;
    }
    __syncthreads();
    // ---- phase B: taps 5-8 ----
#pragma unroll
    for (int kk = 5; kk < 9; ++kk) do_tap(kk, 5);

    // store: lane holds o = obb*16 + q*4 + reg at pixel px -> bf16 pixel-major
    ushort_t* orow = outp + ((size_t)b * kHW + y * kW + px) * 64 + q * 4;
#pragma unroll
    for (int obb = 0; obb < 4; ++obb) {
        float4 bias = *(const float4*)&db[obb * 16 + q * 4];
        f4v v = acc[obb];
        uint2 u;
        u.x = cvtpk(v.x + bias.x, v.y + bias.y);
        u.y = cvtpk(v.z + bias.z, v.w + bias.w);
        *(uint2*)(orow + obb * 16) = u;
    }
}

// ---------------------------------------------------------------------------
// Kernel 4 (round-20/22, verified): attention, two-phase k->v staging.
// ---------------------------------------------------------------------------
__global__ __launch_bounds__(512) void attn_fused(const ushort_t* __restrict__ q0,
                                                  const ushort_t* __restrict__ k0,
                                                  const ushort_t* __restrict__ v0,
                                                  const ushort_t* __restrict__ q1,
                                                  const ushort_t* __restrict__ kd2,
                                                  const ushort_t* __restrict__ vd2,
                                                  const ushort_t* __restrict__ q2,
                                                  const ushort_t* __restrict__ kd3,
                                                  const ushort_t* __restrict__ vd3,
                                                  ushort_t* __restrict__ aopx) {
    __shared__ ushort_t kvs[8 * 4096];      // 64KB: k then v (two-phase)

    const int tid = threadIdx.x;
    const int bx  = blockIdx.x;
    const int lb  = (bx & 7) * 96 + (bx >> 3);  // XCD swizzle (G=768)
    const int zb  = lb >> 8;                // branch 0,1,2
    const int rest = lb & 255;
    const int b   = rest >> 5;
    const int y0  = (rest & 31) * 2;        // first of 2 output rows
    const int dil = zb + 1;
    const int nr  = 2 * dil + 2;            // staged rows
    const int wlo = y0 - dil;

    const ushort_t* qpx = (zb == 0) ? q0 : (zb == 1) ? q1 : q2;
    const ushort_t* kpx = (zb == 0) ? k0 : (zb == 1) ? kd2 : kd3;
    const ushort_t* vpx = (zb == 0) ? v0 : (zb == 1) ? vd2 : vd3;

    const size_t pbase = (size_t)b * kHW;
    const ushort_t* kb = kpx + pbase * 64;
    const ushort_t* vb = vpx + pbase * 64;

    const int stx  = tid >> 3;
    const int stcc = tid & 7;
    const int dstc = (stx * 128 + stcc * 16) ^ ((stx & 7) << 4);

    // ---- phase 1: stage k rows ----
    for (int r = 0; r < nr; ++r) {
        int gy = min(max(wlo + r, 0), kH - 1);
        *(uint4*)((char*)kvs + r * 8192 + dstc) = *(const uint4*)(kb + (size_t)gy * 4096 + tid * 8);
    }
    __syncthreads();

    const int wave = tid >> 6;          // 0..7
    const int l    = tid & 63;
    const int ry   = wave >> 2;         // row within pair
    const int wc   = wave & 3;          // 16-px column group
    const int pxq  = l >> 2;            // 16 pixels per wave
    const int cg   = l & 3;             // 4 channel-groups of 16 ch
    const int y  = y0 + ry;
    const int x_ = wc * 16 + pxq;
    const int p  = y * kW + x_;

    const ushort_t* qb = qpx + (pbase + p) * 64 + cg * 16;
    s8v qv0 = *(const s8v*)qb;
    s8v qv1 = *(const s8v*)(qb + 8);
    float qf[16];
#pragma unroll
    for (int j = 0; j < 8; ++j) { qf[j] = bfu(qv0[j]); qf[8 + j] = bfu(qv1[j]); }

    int a0s[9], a1s[9];
    float msk[9];
#pragma unroll
    for (int kk = 0; kk < 9; ++kk) {
        int dy = (kk / 3 - 1) * dil, dx = (kk % 3 - 1) * dil;
        int yy = y + dy, xx = x_ + dx;
        bool v = (yy >= 0) & (yy < kH) & (xx >= 0) & (xx < kW);
        msk[kk] = v ? 1.f : 0.f;
        int r  = min(max(yy - wlo, 0), nr - 1);
        int xc = min(max(xx, 0), kW - 1);
        int sw = (xc & 7) << 4;
        a0s[kk] = r * 8192 + ((xc * 128 + cg * 32) ^ sw);
        a1s[kk] = r * 8192 + ((xc * 128 + cg * 32 + 16) ^ sw);
    }

    float e[9];
#pragma unroll
    for (int kk = 0; kk < 9; ++kk) {
        s8v k0v = *(const s8v*)((const char*)kvs + a0s[kk]);
        s8v k1v = *(const s8v*)((const char*)kvs + a1s[kk]);
        float s = 0.f;
#pragma unroll
        for (int j = 0; j < 8; ++j) {
            s += qf[j] * bfu(k0v[j]);
            s += qf[8 + j] * bfu(k1v[j]);
        }
        s += __shfl_xor(s, 1);
        s += __shfl_xor(s, 2);
        e[kk] = s * 0.125f * msk[kk];
    }
    float mx = -1e30f;
#pragma unroll
    for (int kk = 0; kk < 9; ++kk) mx = fmaxf(mx, e[kk]);
    float ssum = 0.f;
#pragma unroll
    for (int kk = 0; kk < 9; ++kk) { e[kk] = __expf(e[kk] - mx); ssum += e[kk]; }
    float inv = 1.f / ssum;
#pragma unroll
    for (int kk = 0; kk < 9; ++kk) e[kk] = e[kk] * inv * msk[kk];

    __syncthreads();                     // all k reads done
    // ---- phase 2: restage with v rows ----
    for (int r = 0; r < nr; ++r) {
        int gy = min(max(wlo + r, 0), kH - 1);
        *(uint4*)((char*)kvs + r * 8192 + dstc) = *(const uint4*)(vb + (size_t)gy * 4096 + tid * 8);
    }
    __syncthreads();

    float acc[16];
#pragma unroll
    for (int j = 0; j < 16; ++j) acc[j] = 0.f;
#pragma unroll
    for (int kk = 0; kk < 9; ++kk) {
        s8v v0v = *(const s8v*)((const char*)kvs + a0s[kk]);
        s8v v1v = *(const s8v*)((const char*)kvs + a1s[kk]);
        float w = e[kk];
#pragma unroll
        for (int j = 0; j < 8; ++j) {
            acc[j] += w * bfu(v0v[j]);
            acc[8 + j] += w * bfu(v1v[j]);
        }
    }
    unsigned u[8];
#pragma unroll
    for (int i = 0; i < 8; ++i)
        u[i] = cvtpk(acc[2 * i], acc[2 * i + 1]);
    ushort_t* ob = aopx + (pbase + p) * kC + zb * 64 + cg * 16;
    *(uint4*)ob = make_uint4(u[0], u[1], u[2], u[3]);
    *(uint4*)(ob + 8) = make_uint4(u[4], u[5], u[6], u[7]);
}

// ---------------------------------------------------------------------------
// Kernel 5 (verified): output projection, LDS-staged GEMM. UNCHANGED.
// ---------------------------------------------------------------------------
__global__ __launch_bounds__(256) void proj_mfma3(const ushort_t* __restrict__ aopx,
                                                  const ushort_t* __restrict__ pwbp,
                                                  const float* __restrict__ pb,
                                                  float* __restrict__ out) {
    __shared__ ushort_t xs[64 * kC];            // 24576 B, swizzled rows of 384 B

    const int tid = threadIdx.x;
    const int bx  = blockIdx.x;
    const int lb  = (bx & 7) * 64 + (bx >> 3);  // XCD swizzle (G=512)
    const int m0  = lb * 64;

#pragma unroll
    for (int i = 0; i < 6; ++i) {
        int il = i * 256 + tid;                 // 16B chunk id, 0..1535
        int p  = il / 24;                       // pixel row in strip
        int cc = il % 24;                       // 16B chunk within row
        uint4 v = *(const uint4*)(aopx + (size_t)(m0 + p) * kC + cc * 8);
        int dst = p * 384 + ((cc * 16) ^ ((p & 7) << 4));
        *(uint4*)((char*)xs + dst) = v;
    }
    __syncthreads();

    const int lane = tid & 63;
    const int wave = tid >> 6;
    const int l15  = lane & 15;
    const int q    = lane >> 4;
    const int sbase = wave * 3;                 // strips 0..11, 3 per wave

    f4v acc[3][4];
#pragma unroll
    for (int i = 0; i < 3; ++i)
#pragma unroll
        for (int m = 0; m < 4; ++m) acc[i][m] = (f4v){0.f, 0.f, 0.f, 0.f};

    const ushort_t* ap = pwbp + ((size_t)sbase * 6 * 64 + lane) * 8;

#pragma unroll
    for (int kc = 0; kc < 6; ++kc) {
        s8v bfr[4];
#pragma unroll
        for (int m = 0; m < 4; ++m) {
            int row = m * 16 + l15;
            int col = (kc * 64 + q * 16) ^ ((l15 & 7) << 4);
            bfr[m] = *(const s8v*)((const char*)xs + row * 384 + col);
        }
#pragma unroll
        for (int i = 0; i < 3; ++i) {
            s8v a = *(const s8v*)(ap + (size_t)(i * 6 + kc) * 64 * 8);
#pragma unroll
            for (int m = 0; m < 4; ++m)
                acc[i][m] = __builtin_amdgcn_mfma_f32_16x16x32_bf16(a, bfr[m], acc[i][m], 0, 0, 0);
        }
    }

#pragma unroll
    for (int i = 0; i < 3; ++i) {
        int s  = sbase + i;
        int n0 = s * 16 + q * 4;
        float4 bias = *(const float4*)&pb[n0];
#pragma unroll
        for (int m = 0; m < 4; ++m) {
            f4v v = acc[i][m];
            v.x += bias.x; v.y += bias.y; v.z += bias.z; v.w += bias.w;
            *(f4v*)&out[(size_t)(m0 + m * 16 + l15) * kC + n0] = v;
        }
    }
}

// ---------------------------------------------------------------------------
// Host launcher.  Workspace ~72 MB.
// 6 dispatches: prep_all, qkv(fused cvt), off_fused, deform_big, attn_fused, proj.
// ---------------------------------------------------------------------------
extern "C" void kernel_launch(void* const* d_in, const int* in_sizes, int n_in,
                              void* d_out, int out_size, void* d_ws, size_t ws_size,
                              hipStream_t stream) {
    const float* x      = (const float*)d_in[0];
    const float* qkv_w  = (const float*)d_in[1];
    const float* proj_w = (const float*)d_in[2];
    const float* proj_b = (const float*)d_in[3];
    const float* off_w2 = (const float*)d_in[4];
    const float* off_b2 = (const float*)d_in[5];
    const float* def_w2 = (const float*)d_in[6];
    const float* def_b2 = (const float*)d_in[7];
    const float* off_w3 = (const float*)d_in[8];
    const float* off_b3 = (const float*)d_in[9];
    const float* def_w3 = (const float*)d_in[10];
    const float* def_b3 = (const float*)d_in[11];
    float* out = (float*)d_out;

    float* ws    = (float*)d_ws;
    float* offb2 = ws;                              // 18 * M
    float* offb3 = offb2 + (size_t)18 * kM;         // 18 * M
    ushort_t* us = (ushort_t*)(offb3 + (size_t)18 * kM);
    ushort_t* qkvpx  = us;  us += (size_t)9 * kM * 64;
    ushort_t* kd2    = us;  us += (size_t)kM * 64;
    ushort_t* vd2    = us;  us += (size_t)kM * 64;
    ushort_t* kd3    = us;  us += (size_t)kM * 64;
    ushort_t* vd3    = us;  us += (size_t)kM * 64;
    ushort_t* aopx   = us;  us += (size_t)kM * kC;
    ushort_t* awb    = us;  us += (size_t)kNQKV * kC;   // 36*6*64*8 == 576*192
    ushort_t* pwbp   = us;  us += (size_t)kC * kC;      // 12*6*64*8 == 192*192
    ushort_t* dwtb2  = us;  us += kD * kD * 9;
    ushort_t* dwtb3  = us;  us += kD * kD * 9;
    ushort_t* owtb2  = us;  us += 9 * 32 * 64;
    ushort_t* owtb3  = us;  us += 9 * 32 * 64;

    // 0. weight packs only (x conversion fused into qkv)
    prep_all<<<504, 256, 0, stream>>>(qkv_w, proj_w, def_w2, def_w3, off_w2, off_w3,
                                      awb, pwbp, dwtb2, dwtb3, owtb2, owtb3);

    // per-tensor pixel-major slices
    ushort_t* q0 = qkvpx;
    ushort_t* q1 = qkvpx + (size_t)1 * kM * 64;
    ushort_t* q2 = qkvpx + (size_t)2 * kM * 64;
    ushort_t* k0 = qkvpx + (size_t)3 * kM * 64;
    ushort_t* k1 = qkvpx + (size_t)4 * kM * 64;
    ushort_t* k2 = qkvpx + (size_t)5 * kM * 64;
    ushort_t* v0 = qkvpx + (size_t)6 * kM * 64;
    ushort_t* v1 = qkvpx + (size_t)7 * kM * 64;
    ushort_t* v2 = qkvpx + (size_t)8 * kM * 64;

    // 1. QKV projection with fused f32->bf16 staging
    qkv_mfma4<<<dim3(kM / 64, 3), 256, 0, stream>>>(x, awb, qkvpx);

    // 2. offsets conv, both branches, LDS-staged (one dispatch)
    off_conv_fused<<<1024, 256, 0, stream>>>(k1, k2, owtb2, owtb3,
                                             off_b2, off_b3, offb2, offb3);

    // 3. deformable conv, both branches, 16-wave blocks (one dispatch)
    deform_big<<<512, 1024, 0, stream>>>(k1, v1, k2, v2, offb2, offb3,
                                         dwtb2, dwtb3, def_b2, def_b3,
                                         kd2, vd2, kd3, vd3);

    // 4. attention, all three branches, two-phase k/v staging (one dispatch)
    attn_fused<<<768, 512, 0, stream>>>(q0, k0, v0, q1, kd2, vd2, q2, kd3, vd3, aopx);

    // 5. output projection (LDS-staged bf16 MFMA, fp32 out)
    proj_mfma3<<<512, 256, 0, stream>>>(aopx, pwbp, proj_b, out);
}